// Round 1
// baseline (1634.377 us; speedup 1.0000x reference)
//
#include <hip/hip_runtime.h>

#define NN 200000
#define NE 6400000
#define FIN 512
#define HID 16
#define NC 7
#define NB 782        // ceil(NN/256)
#define EB 25000      // NE/256
#define KC 32

// ---------------- CSR build ----------------

__global__ __launch_bounds__(256) void k_count(const int* __restrict__ dst, int* __restrict__ count) {
    int e = blockIdx.x * 256 + threadIdx.x;
    if (e < NE) atomicAdd(&count[dst[e]], 1);
}

__global__ __launch_bounds__(256) void k_scan1(const int* __restrict__ count, int* __restrict__ starts,
                                               int* __restrict__ partials) {
    __shared__ int tmp[256];
    int tid = threadIdx.x;
    int n = blockIdx.x * 256 + tid;
    int v = (n < NN) ? count[n] : 0;
    tmp[tid] = v;
    __syncthreads();
    #pragma unroll
    for (int off = 1; off < 256; off <<= 1) {
        int t = (tid >= off) ? tmp[tid - off] : 0;
        __syncthreads();
        tmp[tid] += t;
        __syncthreads();
    }
    if (n < NN) starts[n] = tmp[tid] - v;           // block-local exclusive
    if (tid == 255) partials[blockIdx.x] = tmp[tid]; // block total
}

__global__ __launch_bounds__(1024) void k_scan2(int* __restrict__ partials) {
    __shared__ int tmp[1024];
    int i = threadIdx.x;
    int v = (i < NB) ? partials[i] : 0;
    tmp[i] = v;
    __syncthreads();
    #pragma unroll
    for (int off = 1; off < 1024; off <<= 1) {
        int t = (i >= off) ? tmp[i - off] : 0;
        __syncthreads();
        tmp[i] += t;
        __syncthreads();
    }
    if (i < NB) partials[i] = tmp[i] - v;           // exclusive
}

__global__ __launch_bounds__(256) void k_scan3(int* __restrict__ starts, int* __restrict__ cursor,
                                               const int* __restrict__ partials, const int* __restrict__ count,
                                               float* __restrict__ dinv) {
    int n = blockIdx.x * 256 + threadIdx.x;
    if (n >= NN) return;
    int s = starts[n] + partials[blockIdx.x];
    starts[n] = s;
    cursor[n] = s;
    dinv[n] = rsqrtf((float)(count[n] + 1));        // +1 self-loop; deg >= 1 always
}

__global__ __launch_bounds__(256) void k_fill(const int* __restrict__ src, const int* __restrict__ dst,
                                              int* __restrict__ cursor, int* __restrict__ csr_src) {
    int e = blockIdx.x * 256 + threadIdx.x;
    if (e >= NE) return;
    int d = dst[e];
    int pos = atomicAdd(&cursor[d], 1);
    csr_src[pos] = src[e];
}

// ---------------- layer 1 GEMM: h1s = (x @ W1) * dinv ----------------

__global__ __launch_bounds__(256) void k_gemm1(const float* __restrict__ x, const float* __restrict__ W1,
                                               const float* __restrict__ dinv, float* __restrict__ h1s) {
    __shared__ float xs[KC][257];   // transposed tile, pad 257: conflict-free col reads
    const int tid = threadIdx.x;
    const int row0 = blockIdx.x * 256;
    const int row = row0 + tid;
    float acc[HID];
    #pragma unroll
    for (int c = 0; c < HID; ++c) acc[c] = 0.f;

    for (int k0 = 0; k0 < FIN; k0 += KC) {
        __syncthreads();
        // stage 256 rows x 32 k, coalesced float4 (8 lanes cover 128B of one row)
        #pragma unroll
        for (int j = 0; j < 8; ++j) {
            int f = tid + 256 * j;
            int r = f >> 3;
            int kq = f & 7;
            int gr = row0 + r;
            float4 v = make_float4(0.f, 0.f, 0.f, 0.f);
            if (gr < NN) v = *(const float4*)(x + (size_t)gr * FIN + k0 + kq * 4);
            xs[kq * 4 + 0][r] = v.x;
            xs[kq * 4 + 1][r] = v.y;
            xs[kq * 4 + 2][r] = v.z;
            xs[kq * 4 + 3][r] = v.w;
        }
        __syncthreads();
        #pragma unroll 4
        for (int k = 0; k < KC; ++k) {
            float xv = xs[k][tid];
            const float4* w = (const float4*)(W1 + (size_t)(k0 + k) * HID); // uniform -> s_load
            float4 w0 = w[0], w1 = w[1], w2 = w[2], w3 = w[3];
            acc[0]  = fmaf(xv, w0.x, acc[0]);  acc[1]  = fmaf(xv, w0.y, acc[1]);
            acc[2]  = fmaf(xv, w0.z, acc[2]);  acc[3]  = fmaf(xv, w0.w, acc[3]);
            acc[4]  = fmaf(xv, w1.x, acc[4]);  acc[5]  = fmaf(xv, w1.y, acc[5]);
            acc[6]  = fmaf(xv, w1.z, acc[6]);  acc[7]  = fmaf(xv, w1.w, acc[7]);
            acc[8]  = fmaf(xv, w2.x, acc[8]);  acc[9]  = fmaf(xv, w2.y, acc[9]);
            acc[10] = fmaf(xv, w2.z, acc[10]); acc[11] = fmaf(xv, w2.w, acc[11]);
            acc[12] = fmaf(xv, w3.x, acc[12]); acc[13] = fmaf(xv, w3.y, acc[13]);
            acc[14] = fmaf(xv, w3.z, acc[14]); acc[15] = fmaf(xv, w3.w, acc[15]);
        }
    }
    if (row < NN) {
        float dv = dinv[row];
        float4* o = (float4*)(h1s + (size_t)row * HID);
        o[0] = make_float4(acc[0] * dv, acc[1] * dv, acc[2] * dv, acc[3] * dv);
        o[1] = make_float4(acc[4] * dv, acc[5] * dv, acc[6] * dv, acc[7] * dv);
        o[2] = make_float4(acc[8] * dv, acc[9] * dv, acc[10] * dv, acc[11] * dv);
        o[3] = make_float4(acc[12] * dv, acc[13] * dv, acc[14] * dv, acc[15] * dv);
    }
}

// ---------------- fused agg1 + bias + relu + @W2 + prescale ----------------

__device__ __forceinline__ void add16(float* acc, const float* p) {
    const float4* q = (const float4*)p;
    float4 a = q[0], b = q[1], c = q[2], d = q[3];
    acc[0] += a.x;  acc[1] += a.y;  acc[2] += a.z;  acc[3] += a.w;
    acc[4] += b.x;  acc[5] += b.y;  acc[6] += b.z;  acc[7] += b.w;
    acc[8] += c.x;  acc[9] += c.y;  acc[10] += c.z; acc[11] += c.w;
    acc[12] += d.x; acc[13] += d.y; acc[14] += d.z; acc[15] += d.w;
}

__global__ __launch_bounds__(256) void k_agg1(const int* __restrict__ starts, const int* __restrict__ count,
                                              const int* __restrict__ csr_src, const float* __restrict__ h1s,
                                              const float* __restrict__ dinv, const float* __restrict__ b1,
                                              const float* __restrict__ W2, float* __restrict__ h2s) {
    int n = blockIdx.x * 256 + threadIdx.x;
    if (n >= NN) return;
    float acc[HID];
    add16_init: {
        const float4* q = (const float4*)(h1s + (size_t)n * HID);   // self-loop term
        float4 a = q[0], b = q[1], c = q[2], d = q[3];
        acc[0] = a.x;  acc[1] = a.y;  acc[2] = a.z;  acc[3] = a.w;
        acc[4] = b.x;  acc[5] = b.y;  acc[6] = b.z;  acc[7] = b.w;
        acc[8] = c.x;  acc[9] = c.y;  acc[10] = c.z; acc[11] = c.w;
        acc[12] = d.x; acc[13] = d.y; acc[14] = d.z; acc[15] = d.w;
    }
    int beg = starts[n];
    int end = beg + count[n];
    int i = beg;
    for (; i + 3 < end; i += 4) {                   // 4-wide for memory-level parallelism
        int s0 = csr_src[i], s1 = csr_src[i + 1], s2 = csr_src[i + 2], s3 = csr_src[i + 3];
        add16(acc, h1s + (size_t)s0 * HID);
        add16(acc, h1s + (size_t)s1 * HID);
        add16(acc, h1s + (size_t)s2 * HID);
        add16(acc, h1s + (size_t)s3 * HID);
    }
    for (; i < end; ++i) add16(acc, h1s + (size_t)csr_src[i] * HID);

    float dv = dinv[n];
    float h[HID];
    #pragma unroll
    for (int c = 0; c < HID; ++c) h[c] = fmaxf(fmaf(dv, acc[c], b1[c]), 0.f);
    float z[8];
    #pragma unroll
    for (int j = 0; j < NC; ++j) {
        float t = 0.f;
        #pragma unroll
        for (int c = 0; c < HID; ++c) t = fmaf(h[c], W2[c * NC + j], t);
        z[j] = t * dv;
    }
    z[7] = 0.f;
    float4* o = (float4*)(h2s + (size_t)n * 8);
    o[0] = make_float4(z[0], z[1], z[2], z[3]);
    o[1] = make_float4(z[4], z[5], z[6], z[7]);
}

// ---------------- fused agg2 + bias -> out ----------------

__global__ __launch_bounds__(256) void k_agg2(const int* __restrict__ starts, const int* __restrict__ count,
                                              const int* __restrict__ csr_src, const float* __restrict__ h2s,
                                              const float* __restrict__ dinv, const float* __restrict__ b2,
                                              float* __restrict__ out) {
    int n = blockIdx.x * 256 + threadIdx.x;
    if (n >= NN) return;
    float acc[8];
    {
        const float4* q = (const float4*)(h2s + (size_t)n * 8);     // self-loop term
        float4 a = q[0], b = q[1];
        acc[0] = a.x; acc[1] = a.y; acc[2] = a.z; acc[3] = a.w;
        acc[4] = b.x; acc[5] = b.y; acc[6] = b.z; acc[7] = b.w;
    }
    int beg = starts[n];
    int end = beg + count[n];
    int i = beg;
    for (; i + 3 < end; i += 4) {
        int s0 = csr_src[i], s1 = csr_src[i + 1], s2 = csr_src[i + 2], s3 = csr_src[i + 3];
        const float4 *p0 = (const float4*)(h2s + (size_t)s0 * 8), *p1 = (const float4*)(h2s + (size_t)s1 * 8);
        const float4 *p2 = (const float4*)(h2s + (size_t)s2 * 8), *p3 = (const float4*)(h2s + (size_t)s3 * 8);
        float4 a0 = p0[0], b0 = p0[1], a1 = p1[0], b1 = p1[1];
        float4 a2 = p2[0], b2v = p2[1], a3 = p3[0], b3 = p3[1];
        acc[0] += a0.x + a1.x + a2.x + a3.x;
        acc[1] += a0.y + a1.y + a2.y + a3.y;
        acc[2] += a0.z + a1.z + a2.z + a3.z;
        acc[3] += a0.w + a1.w + a2.w + a3.w;
        acc[4] += b0.x + b1.x + b2v.x + b3.x;
        acc[5] += b0.y + b1.y + b2v.y + b3.y;
        acc[6] += b0.z + b1.z + b2v.z + b3.z;
    }
    for (; i < end; ++i) {
        const float4* p = (const float4*)(h2s + (size_t)csr_src[i] * 8);
        float4 a = p[0], b = p[1];
        acc[0] += a.x; acc[1] += a.y; acc[2] += a.z; acc[3] += a.w;
        acc[4] += b.x; acc[5] += b.y; acc[6] += b.z;
    }
    float dv = dinv[n];
    #pragma unroll
    for (int j = 0; j < NC; ++j) out[(size_t)n * NC + j] = fmaf(dv, acc[j], b2[j]);
}

// ---------------- launch ----------------

extern "C" void kernel_launch(void* const* d_in, const int* in_sizes, int n_in,
                              void* d_out, int out_size, void* d_ws, size_t ws_size,
                              hipStream_t stream) {
    const float* x  = (const float*)d_in[0];
    const int*   ei = (const int*)d_in[1];
    const float* W1 = (const float*)d_in[2];
    const float* b1 = (const float*)d_in[3];
    const float* W2 = (const float*)d_in[4];
    const float* b2 = (const float*)d_in[5];
    const int* src = ei;
    const int* dst = ei + NE;
    float* out = (float*)d_out;

    char* ws = (char*)d_ws;
    size_t o = 0;
    auto alloc = [&](size_t bytes) {
        char* p = ws + o;
        o = (o + bytes + 255) & ~(size_t)255;
        return p;
    };
    int*   count    = (int*)alloc((size_t)NN * 4);
    int*   starts   = (int*)alloc((size_t)NN * 4);
    int*   cursor   = (int*)alloc((size_t)NN * 4);
    int*   partials = (int*)alloc(1024 * 4);
    int*   csr_src  = (int*)alloc((size_t)NE * 4);
    float* dinv     = (float*)alloc((size_t)NN * 4);
    float* h1s      = (float*)alloc((size_t)NN * HID * 4);
    float* h2s      = (float*)alloc((size_t)NN * 8 * 4);

    hipMemsetAsync(count, 0, (size_t)NN * 4, stream);
    k_count<<<EB, 256, 0, stream>>>(dst, count);
    k_scan1<<<NB, 256, 0, stream>>>(count, starts, partials);
    k_scan2<<<1, 1024, 0, stream>>>(partials);
    k_scan3<<<NB, 256, 0, stream>>>(starts, cursor, partials, count, dinv);
    k_fill<<<EB, 256, 0, stream>>>(src, dst, cursor, csr_src);
    k_gemm1<<<NB, 256, 0, stream>>>(x, W1, dinv, h1s);
    k_agg1<<<NB, 256, 0, stream>>>(starts, count, csr_src, h1s, dinv, b1, W2, h2s);
    k_agg2<<<NB, 256, 0, stream>>>(starts, count, csr_src, h2s, dinv, b2, out);
}

// Round 2
// 1000.198 us; speedup vs baseline: 1.6341x; 1.6341x over previous
//
#include <hip/hip_runtime.h>

#define NN 200000
#define NE 6400000
#define FIN 512
#define HID 16
#define NC 7
#define NB 782        // ceil(NN/256)  (also = bucket count, nodes/bucket = 256)
#define K  782        // buckets: bucket = dst >> 8
#define CH 8192       // edges per block in bucket sort
#define EB2 782       // ceil(NE/CH)
#define KC 32

// ================= bucketed CSR build (atomic-light, L2-friendly) =================

__global__ __launch_bounds__(256) void k_bcount(const int* __restrict__ dst, int* __restrict__ bucket_total) {
    __shared__ int hist[K];
    int tid = threadIdx.x;
    long e0 = (long)blockIdx.x * CH;
    int cnt = (int)min((long)CH, (long)NE - e0);
    for (int i = tid; i < K; i += 256) hist[i] = 0;
    __syncthreads();
    for (int i = tid; i < cnt; i += 256) atomicAdd(&hist[dst[e0 + i] >> 8], 1);
    __syncthreads();
    for (int b = tid; b < K; b += 256) {
        int h = hist[b];
        if (h) atomicAdd(&bucket_total[b], h);
    }
}

__global__ __launch_bounds__(1024) void k_bscan(const int* __restrict__ bucket_total,
                                                int* __restrict__ bucket_base, int* __restrict__ bucket_cursor) {
    __shared__ int tmp[1024];
    int i = threadIdx.x;
    int v = (i < K) ? bucket_total[i] : 0;
    tmp[i] = v;
    __syncthreads();
    #pragma unroll
    for (int off = 1; off < 1024; off <<= 1) {
        int t = (i >= off) ? tmp[i - off] : 0;
        __syncthreads();
        tmp[i] += t;
        __syncthreads();
    }
    if (i < K) {
        int base = tmp[i] - v;
        bucket_base[i] = base;
        bucket_cursor[i] = base;
    }
    if (i == K - 1) bucket_base[K] = tmp[i];
}

// bin-sort CH edges in LDS, write packed words (loc<<24 | src) in bucket-contiguous runs
__global__ __launch_bounds__(256) void k_bfill(const int* __restrict__ src, const int* __restrict__ dst,
                                               int* __restrict__ bucket_cursor, unsigned int* __restrict__ bwords) {
    __shared__ int hist[K];
    __shared__ int ofs0[K];
    __shared__ int gb2[K];
    __shared__ int ptmp[256];
    __shared__ unsigned long long stage[CH];
    int tid = threadIdx.x;
    long e0 = (long)blockIdx.x * CH;
    int cnt = (int)min((long)CH, (long)NE - e0);

    for (int i = tid; i < K; i += 256) hist[i] = 0;
    __syncthreads();
    for (int i = tid; i < cnt; i += 256) atomicAdd(&hist[dst[e0 + i] >> 8], 1);
    __syncthreads();

    // block-exclusive scan over K bins: thread t owns bins 4t..4t+3
    int b0 = tid * 4;
    int h0 = (b0 + 0 < K) ? hist[b0 + 0] : 0;
    int h1 = (b0 + 1 < K) ? hist[b0 + 1] : 0;
    int h2 = (b0 + 2 < K) ? hist[b0 + 2] : 0;
    int h3 = (b0 + 3 < K) ? hist[b0 + 3] : 0;
    int s = h0 + h1 + h2 + h3;
    ptmp[tid] = s;
    __syncthreads();
    #pragma unroll
    for (int off = 1; off < 256; off <<= 1) {
        int t = (tid >= off) ? ptmp[tid - off] : 0;
        __syncthreads();
        ptmp[tid] += t;
        __syncthreads();
    }
    int run = ptmp[tid] - s;    // exclusive prefix of this thread's 4 bins
    if (b0 + 0 < K) { ofs0[b0 + 0] = run; run += h0; }
    if (b0 + 1 < K) { ofs0[b0 + 1] = run; run += h1; }
    if (b0 + 2 < K) { ofs0[b0 + 2] = run; run += h2; }
    if (b0 + 3 < K) { ofs0[b0 + 3] = run; run += h3; }
    __syncthreads();

    // reserve global ranges per bin; gb2 = global_base - local_base
    for (int b = tid; b < K; b += 256) {
        int h = hist[b];
        int g = h ? atomicAdd(&bucket_cursor[b], h) : 0;
        gb2[b] = g - ofs0[b];
    }
    __syncthreads();
    // reuse hist as rank counters
    for (int b = tid; b < K; b += 256) hist[b] = 0;
    __syncthreads();

    for (int i = tid; i < cnt; i += 256) {
        int d = dst[e0 + i];
        int sv = src[e0 + i];
        int bin = d >> 8;
        int r = atomicAdd(&hist[bin], 1);
        unsigned int word = ((unsigned int)(d & 255) << 24) | (unsigned int)sv;  // src < 2^24
        stage[ofs0[bin] + r] = ((unsigned long long)(unsigned int)d << 32) | word;
    }
    __syncthreads();
    // write out bin-sorted: contiguous runs per (block,bin)
    for (int i = tid; i < cnt; i += 256) {
        unsigned long long p = stage[i];
        int bin = (int)(p >> 40);          // (d >> 8)
        bwords[gb2[bin] + i] = (unsigned int)p;
    }
}

// one block per bucket: build csr_src + starts/count/dinv; scatter stays in a 32KB L2 window
__global__ __launch_bounds__(256) void k_bcsr(const unsigned int* __restrict__ bwords,
                                              const int* __restrict__ bucket_base,
                                              int* __restrict__ csr_src, int* __restrict__ starts,
                                              int* __restrict__ count, float* __restrict__ dinv) {
    __shared__ int cnt[256];
    __shared__ int st[256];
    int b = blockIdx.x;
    int tid = threadIdx.x;
    int n0 = b << 8;
    int p0 = bucket_base[b];
    int p1 = bucket_base[b + 1];
    cnt[tid] = 0;
    __syncthreads();
    for (int i = p0 + tid; i < p1; i += 256) {
        unsigned int w = bwords[i];
        atomicAdd(&cnt[w >> 24], 1);
    }
    __syncthreads();
    int v = cnt[tid];
    st[tid] = v;
    __syncthreads();
    #pragma unroll
    for (int off = 1; off < 256; off <<= 1) {
        int t = (tid >= off) ? st[tid - off] : 0;
        __syncthreads();
        st[tid] += t;
        __syncthreads();
    }
    int myst = st[tid] - v;   // local exclusive
    int n = n0 + tid;
    if (n < NN) {
        starts[n] = p0 + myst;
        count[n] = v;
        dinv[n] = rsqrtf((float)(v + 1));
    }
    __syncthreads();
    st[tid] = myst;
    cnt[tid] = 0;
    __syncthreads();
    for (int i = p0 + tid; i < p1; i += 256) {
        unsigned int w = bwords[i];
        int loc = w >> 24;
        int r = atomicAdd(&cnt[loc], 1);
        csr_src[p0 + st[loc] + r] = (int)(w & 0xFFFFFFu);
    }
}

// ================= layer 1 GEMM: h1s = (x @ W1) * dinv =================

__global__ __launch_bounds__(256) void k_gemm1(const float* __restrict__ x, const float* __restrict__ W1,
                                               const float* __restrict__ dinv, float* __restrict__ h1s) {
    __shared__ float xs[KC][257];
    const int tid = threadIdx.x;
    const int row0 = blockIdx.x * 256;
    const int row = row0 + tid;
    float acc[HID];
    #pragma unroll
    for (int c = 0; c < HID; ++c) acc[c] = 0.f;

    for (int k0 = 0; k0 < FIN; k0 += KC) {
        __syncthreads();
        #pragma unroll
        for (int j = 0; j < 8; ++j) {
            int f = tid + 256 * j;
            int r = f >> 3;
            int kq = f & 7;
            int gr = row0 + r;
            float4 v = make_float4(0.f, 0.f, 0.f, 0.f);
            if (gr < NN) v = *(const float4*)(x + (size_t)gr * FIN + k0 + kq * 4);
            xs[kq * 4 + 0][r] = v.x;
            xs[kq * 4 + 1][r] = v.y;
            xs[kq * 4 + 2][r] = v.z;
            xs[kq * 4 + 3][r] = v.w;
        }
        __syncthreads();
        #pragma unroll 4
        for (int k = 0; k < KC; ++k) {
            float xv = xs[k][tid];
            const float4* w = (const float4*)(W1 + (size_t)(k0 + k) * HID);
            float4 w0 = w[0], w1 = w[1], w2 = w[2], w3 = w[3];
            acc[0]  = fmaf(xv, w0.x, acc[0]);  acc[1]  = fmaf(xv, w0.y, acc[1]);
            acc[2]  = fmaf(xv, w0.z, acc[2]);  acc[3]  = fmaf(xv, w0.w, acc[3]);
            acc[4]  = fmaf(xv, w1.x, acc[4]);  acc[5]  = fmaf(xv, w1.y, acc[5]);
            acc[6]  = fmaf(xv, w1.z, acc[6]);  acc[7]  = fmaf(xv, w1.w, acc[7]);
            acc[8]  = fmaf(xv, w2.x, acc[8]);  acc[9]  = fmaf(xv, w2.y, acc[9]);
            acc[10] = fmaf(xv, w2.z, acc[10]); acc[11] = fmaf(xv, w2.w, acc[11]);
            acc[12] = fmaf(xv, w3.x, acc[12]); acc[13] = fmaf(xv, w3.y, acc[13]);
            acc[14] = fmaf(xv, w3.z, acc[14]); acc[15] = fmaf(xv, w3.w, acc[15]);
        }
    }
    if (row < NN) {
        float dv = dinv[row];
        float4* o = (float4*)(h1s + (size_t)row * HID);
        o[0] = make_float4(acc[0] * dv, acc[1] * dv, acc[2] * dv, acc[3] * dv);
        o[1] = make_float4(acc[4] * dv, acc[5] * dv, acc[6] * dv, acc[7] * dv);
        o[2] = make_float4(acc[8] * dv, acc[9] * dv, acc[10] * dv, acc[11] * dv);
        o[3] = make_float4(acc[12] * dv, acc[13] * dv, acc[14] * dv, acc[15] * dv);
    }
}

// ================= fused agg1 + bias + relu + @W2 + prescale =================

__device__ __forceinline__ void add16(float* acc, const float* p) {
    const float4* q = (const float4*)p;
    float4 a = q[0], b = q[1], c = q[2], d = q[3];
    acc[0] += a.x;  acc[1] += a.y;  acc[2] += a.z;  acc[3] += a.w;
    acc[4] += b.x;  acc[5] += b.y;  acc[6] += b.z;  acc[7] += b.w;
    acc[8] += c.x;  acc[9] += c.y;  acc[10] += c.z; acc[11] += c.w;
    acc[12] += d.x; acc[13] += d.y; acc[14] += d.z; acc[15] += d.w;
}

__global__ __launch_bounds__(256) void k_agg1(const int* __restrict__ starts, const int* __restrict__ count,
                                              const int* __restrict__ csr_src, const float* __restrict__ h1s,
                                              const float* __restrict__ dinv, const float* __restrict__ b1,
                                              const float* __restrict__ W2, float* __restrict__ h2s) {
    int n = blockIdx.x * 256 + threadIdx.x;
    if (n >= NN) return;
    float acc[HID];
    {
        const float4* q = (const float4*)(h1s + (size_t)n * HID);   // self-loop term
        float4 a = q[0], b = q[1], c = q[2], d = q[3];
        acc[0] = a.x;  acc[1] = a.y;  acc[2] = a.z;  acc[3] = a.w;
        acc[4] = b.x;  acc[5] = b.y;  acc[6] = b.z;  acc[7] = b.w;
        acc[8] = c.x;  acc[9] = c.y;  acc[10] = c.z; acc[11] = c.w;
        acc[12] = d.x; acc[13] = d.y; acc[14] = d.z; acc[15] = d.w;
    }
    int beg = starts[n];
    int end = beg + count[n];
    int i = beg;
    for (; i + 3 < end; i += 4) {
        int s0 = csr_src[i], s1 = csr_src[i + 1], s2 = csr_src[i + 2], s3 = csr_src[i + 3];
        add16(acc, h1s + (size_t)s0 * HID);
        add16(acc, h1s + (size_t)s1 * HID);
        add16(acc, h1s + (size_t)s2 * HID);
        add16(acc, h1s + (size_t)s3 * HID);
    }
    for (; i < end; ++i) add16(acc, h1s + (size_t)csr_src[i] * HID);

    float dv = dinv[n];
    float h[HID];
    #pragma unroll
    for (int c = 0; c < HID; ++c) h[c] = fmaxf(fmaf(dv, acc[c], b1[c]), 0.f);
    float z[8];
    #pragma unroll
    for (int j = 0; j < NC; ++j) {
        float t = 0.f;
        #pragma unroll
        for (int c = 0; c < HID; ++c) t = fmaf(h[c], W2[c * NC + j], t);
        z[j] = t * dv;
    }
    z[7] = 0.f;
    float4* o = (float4*)(h2s + (size_t)n * 8);
    o[0] = make_float4(z[0], z[1], z[2], z[3]);
    o[1] = make_float4(z[4], z[5], z[6], z[7]);
}

// ================= fused agg2 + bias -> out =================

__global__ __launch_bounds__(256) void k_agg2(const int* __restrict__ starts, const int* __restrict__ count,
                                              const int* __restrict__ csr_src, const float* __restrict__ h2s,
                                              const float* __restrict__ dinv, const float* __restrict__ b2,
                                              float* __restrict__ out) {
    int n = blockIdx.x * 256 + threadIdx.x;
    if (n >= NN) return;
    float acc[8];
    {
        const float4* q = (const float4*)(h2s + (size_t)n * 8);     // self-loop term
        float4 a = q[0], b = q[1];
        acc[0] = a.x; acc[1] = a.y; acc[2] = a.z; acc[3] = a.w;
        acc[4] = b.x; acc[5] = b.y; acc[6] = b.z; acc[7] = b.w;
    }
    int beg = starts[n];
    int end = beg + count[n];
    int i = beg;
    for (; i + 3 < end; i += 4) {
        int s0 = csr_src[i], s1 = csr_src[i + 1], s2 = csr_src[i + 2], s3 = csr_src[i + 3];
        const float4 *p0 = (const float4*)(h2s + (size_t)s0 * 8), *p1 = (const float4*)(h2s + (size_t)s1 * 8);
        const float4 *p2 = (const float4*)(h2s + (size_t)s2 * 8), *p3 = (const float4*)(h2s + (size_t)s3 * 8);
        float4 a0 = p0[0], b0 = p0[1], a1 = p1[0], b1 = p1[1];
        float4 a2 = p2[0], b2v = p2[1], a3 = p3[0], b3 = p3[1];
        acc[0] += a0.x + a1.x + a2.x + a3.x;
        acc[1] += a0.y + a1.y + a2.y + a3.y;
        acc[2] += a0.z + a1.z + a2.z + a3.z;
        acc[3] += a0.w + a1.w + a2.w + a3.w;
        acc[4] += b0.x + b1.x + b2v.x + b3.x;
        acc[5] += b0.y + b1.y + b2v.y + b3.y;
        acc[6] += b0.z + b1.z + b2v.z + b3.z;
    }
    for (; i < end; ++i) {
        const float4* p = (const float4*)(h2s + (size_t)csr_src[i] * 8);
        float4 a = p[0], b = p[1];
        acc[0] += a.x; acc[1] += a.y; acc[2] += a.z; acc[3] += a.w;
        acc[4] += b.x; acc[5] += b.y; acc[6] += b.z;
    }
    float dv = dinv[n];
    #pragma unroll
    for (int j = 0; j < NC; ++j) out[(size_t)n * NC + j] = fmaf(dv, acc[j], b2[j]);
}

// ================= launch =================

extern "C" void kernel_launch(void* const* d_in, const int* in_sizes, int n_in,
                              void* d_out, int out_size, void* d_ws, size_t ws_size,
                              hipStream_t stream) {
    const float* x  = (const float*)d_in[0];
    const int*   ei = (const int*)d_in[1];
    const float* W1 = (const float*)d_in[2];
    const float* b1 = (const float*)d_in[3];
    const float* W2 = (const float*)d_in[4];
    const float* b2 = (const float*)d_in[5];
    const int* src = ei;
    const int* dst = ei + NE;
    float* out = (float*)d_out;

    char* ws = (char*)d_ws;
    size_t o = 0;
    auto alloc = [&](size_t bytes) {
        char* p = ws + o;
        o = (o + bytes + 255) & ~(size_t)255;
        return p;
    };
    int*   bucket_total  = (int*)alloc((size_t)(K + 1) * 4);
    int*   bucket_base   = (int*)alloc((size_t)(K + 1) * 4);
    int*   bucket_cursor = (int*)alloc((size_t)(K + 1) * 4);
    unsigned int* bwords = (unsigned int*)alloc((size_t)NE * 4);
    int*   csr_src  = (int*)alloc((size_t)NE * 4);
    int*   starts   = (int*)alloc((size_t)NN * 4);
    int*   count    = (int*)alloc((size_t)NN * 4);
    float* dinv     = (float*)alloc((size_t)NN * 4);
    float* h1s      = (float*)alloc((size_t)NN * HID * 4);
    float* h2s      = (float*)alloc((size_t)NN * 8 * 4);

    hipMemsetAsync(bucket_total, 0, (size_t)(K + 1) * 4, stream);
    k_bcount<<<EB2, 256, 0, stream>>>(dst, bucket_total);
    k_bscan<<<1, 1024, 0, stream>>>(bucket_total, bucket_base, bucket_cursor);
    k_bfill<<<EB2, 256, 0, stream>>>(src, dst, bucket_cursor, bwords);
    k_bcsr<<<K, 256, 0, stream>>>(bwords, bucket_base, csr_src, starts, count, dinv);
    k_gemm1<<<NB, 256, 0, stream>>>(x, W1, dinv, h1s);
    k_agg1<<<NB, 256, 0, stream>>>(starts, count, csr_src, h1s, dinv, b1, W2, h2s);
    k_agg2<<<NB, 256, 0, stream>>>(starts, count, csr_src, h2s, dinv, b2, out);
}